// Round 8
// baseline (104.562 us; speedup 1.0000x reference)
//
#include <hip/hip_runtime.h>
#include <math.h>

#define L_SEQ 384
#define E_DIM 512
#define NHEAD 8
#define NBH   16
#define HD    64
#define LOG2E 1.44269504f

typedef __attribute__((ext_vector_type(8))) __bf16 bf16x8;
typedef __attribute__((ext_vector_type(8))) _Float16 f16x8;
typedef __attribute__((ext_vector_type(4))) float f32x4;

union u4h8 { uint4 u; f16x8 h; };

__device__ __forceinline__ float uniform_f(float v) {
  return __uint_as_float(__builtin_amdgcn_readfirstlane(__float_as_uint(v)));
}

__device__ __forceinline__ unsigned f2bf(float f) {   // RNE float->bf16 bits
  unsigned u = __float_as_uint(f);
  return (u + 0x7FFFu + ((u >> 16) & 1u)) >> 16;
}

__device__ __forceinline__ unsigned ror16(unsigned x) { return (x >> 16) | (x << 16); }

// quad_perm DPP: butterfly over the 4 lanes of each aligned 4-lane group
__device__ __forceinline__ float dpp_xor1(float x) {
  return __int_as_float(__builtin_amdgcn_mov_dpp(__float_as_int(x), 0xB1, 0xF, 0xF, 0));
}
__device__ __forceinline__ float dpp_xor2(float x) {
  return __int_as_float(__builtin_amdgcn_mov_dpp(__float_as_int(x), 0x4E, 0xF, 0xF, 0));
}
template <int IMM>
__device__ __forceinline__ float swz_xor(float x) {   // ds_swizzle: imm must be literal
  return __int_as_float(__builtin_amdgcn_ds_swizzle(__float_as_int(x), IMM));
}

// Fragment-packed layout: a wave consumes one (16-row x 32-k) tile as
// lane(quad,mr) -> row=mr, k=quad*8..+7. Pack memory in exactly that order:
// [row/16][k/32][quad=(k>>3)&3][mr=row&15][e=k&7] -> coalesced 16B/lane loads.
__device__ __forceinline__ size_t pidx(int row, int k, int Kd) {
  return ((((size_t)(row >> 4) * (Kd >> 5) + (k >> 5)) * 4 + ((k >> 3) & 3)) * 16
          + (row & 15)) * 8 + (k & 7);
}

// ---------------------------------------------------------------------------
// Convert x|Wq|Wk|Wv (dst1) and Wo (dst2) to bf16 packed; also zero `out`
// (needed by the K-split atomic out-gemm; this kernel runs first).
// ---------------------------------------------------------------------------
__global__ __launch_bounds__(256) void to_bf16_all(
    const float* __restrict__ x, const float* __restrict__ Wq,
    const float* __restrict__ Wk, const float* __restrict__ Wv,
    const float* __restrict__ Wo, unsigned short* __restrict__ dst1,
    unsigned short* __restrict__ dst2, float* __restrict__ outz)
{
  int e0 = (blockIdx.x * 256 + threadIdx.x) * 4;
  if (e0 >= 1835008) return;
  if (e0 >= 1441792) {                       // zero the output buffer
    *(float4*)(outz + (e0 - 1441792)) = make_float4(0.f, 0.f, 0.f, 0.f);
    return;
  }
  const float* src; unsigned short* d; int s;
  if (e0 < 393216)       { src = x;  s = e0;           d = dst1; }
  else if (e0 < 655360)  { src = Wq; s = e0 - 393216;  d = dst1 + 393216; }
  else if (e0 < 917504)  { src = Wk; s = e0 - 655360;  d = dst1 + 655360; }
  else if (e0 < 1179648) { src = Wv; s = e0 - 917504;  d = dst1 + 917504; }
  else                   { src = Wo; s = e0 - 1179648; d = dst2; }
  float4 v = *(const float4*)(src + s);
  unsigned lo = f2bf(v.x) | (f2bf(v.y) << 16);
  unsigned hi = f2bf(v.z) | (f2bf(v.w) << 16);
  int row = s >> 9, k = s & 511;
  *(uint2*)(d + pidx(row, k, 512)) = make_uint2(lo, hi);
}

// ---------------------------------------------------------------------------
// QKV GEMM: bf16 MFMA, packed-fragment operands. C = A @ B^T. tile 64x16.
// z selects B/C; epilogue: per-atom quaternion normalize (DPP quad-sum
// across the 4 component lanes) for z<2, then packed-f16 store
// (row=(b*8+h)*L+l, k=d, Kd=64). grid (32, 12, 3) = 1152 blocks.
// ---------------------------------------------------------------------------
__global__ __launch_bounds__(256) void gemm_qkv(
    const __bf16* __restrict__ A, const __bf16* __restrict__ B0,
    const __bf16* __restrict__ B1, const __bf16* __restrict__ B2,
    float* __restrict__ C0, float* __restrict__ C1, float* __restrict__ C2,
    int M, int N, int K)
{
  const int z = blockIdx.z;
  const __bf16* Bm = (z == 0) ? B0 : (z == 1) ? B1 : B2;
  float* Cp = (z == 0) ? C0 : (z == 1) ? C1 : C2;

  const int tid = threadIdx.x;
  const int wave = tid >> 6, lane = tid & 63;
  const int m0 = blockIdx.y * 64 + wave * 16;
  const int n0 = blockIdx.x * 16;
  const int mr = lane & 15, quad = lane >> 4;
  const int KT = K >> 5;

  f32x4 acc = (f32x4){0.f, 0.f, 0.f, 0.f};

  const __bf16* ap = A + (size_t)(m0 >> 4) * KT * 512 + lane * 8;
  const __bf16* bp = Bm + (size_t)(n0 >> 4) * KT * 512 + lane * 8;

  #pragma unroll 4
  for (int ks = 0; ks < KT; ++ks) {
    bf16x8 a = *(const bf16x8*)(ap + (size_t)ks * 512);
    bf16x8 b = *(const bf16x8*)(bp + (size_t)ks * 512);
    acc = __builtin_amdgcn_mfma_f32_16x16x32_bf16(a, b, acc, 0, 0, 0);
  }

  _Float16* Hp = (_Float16*)Cp;
  int n = n0 + mr;
  #pragma unroll
  for (int r = 0; r < 4; ++r) {
    float val = acc[r];
    float s = val * val;
    s += dpp_xor1(s);
    s += dpp_xor2(s);            // |atom|^2 across the 4 component lanes
    float sc = (z == 2) ? 1.f : __builtin_amdgcn_rsqf(fmaxf(s, 1e-30f));
    int m = m0 + quad * 4 + r;
    int b = m / L_SEQ, l = m - b * L_SEQ;
    int row = (b * NHEAD + (n >> 6)) * L_SEQ + l;
    Hp[pidx(row, n & 63, 64)] = (_Float16)(val * sc);
  }
}

// ---------------------------------------------------------------------------
// z_build: Z0[bh][col=(a,b,e)][j] = khat_b(j,a) * v_e(j,a), packed f16.
// grid (6 j-blocks, 4 a-groups, 16 bh) x 256.
// ---------------------------------------------------------------------------
__global__ __launch_bounds__(256) void z_build(
    const _Float16* __restrict__ khh, const _Float16* __restrict__ vhh,
    _Float16* __restrict__ Z0)
{
  const int tid = threadIdx.x;
  const int l = blockIdx.x * 64 + (tid & 63);
  const int a = blockIdx.y * 4 + (tid >> 6);
  const int bh = blockIdx.z;

  size_t off = pidx(bh * L_SEQ + l, a * 4, 64);
  union { uint2 u; _Float16 h[4]; } kk, vv;
  kk.u = *(const uint2*)(khh + off);
  vv.u = *(const uint2*)(vhh + off);

  float kb[4] = {(float)kk.h[0], (float)kk.h[1], (float)kk.h[2], (float)kk.h[3]};
  float ve[4] = {(float)vv.h[0], (float)vv.h[1], (float)vv.h[2], (float)vv.h[3]};
  _Float16* zp = Z0 + (size_t)bh * (256 * 384);
  #pragma unroll
  for (int b = 0; b < 4; ++b)
    #pragma unroll
    for (int e = 0; e < 4; ++e)
      zp[pidx(a * 16 + b * 4 + e, l, 384)] = (_Float16)(kb[b] * ve[e]);
}

// ---------------------------------------------------------------------------
// gate_pv v3: score-once fusion + J-SPLIT x2. Block (i-strip 16, bh, jh)
// handles 3 of the 6 64-j chunks -> grid (24,16,2) = 768 blocks (3/CU,
// 12 waves/CU; was 384 blocks = 1.5/CU, barrier-latency-exposed).
// Per chunk: SCORE (wave w: own 16-j subtile, all 4 c, 8 MFMA) -> GATE
// (16 sigmoids/lane -> f16 LDS gbuf in A-frag order, dbuf'd, 1 barrier)
// -> PV (wave w = cg: 32 MFMA vs Z0). Epilogue: intra-wave Klein butterfly
// (signed-qhat, ds_swizzle b-reduce, permuted dpp e-stages), lane mr==0
// stores f32 float4 partial ctx into CTXS slab jh (packed layout, Kd=512).
// The two slabs are summed in f32 by out_gemm before ONE bf16 round --
// bit-identical to the unsplit path.
// ---------------------------------------------------------------------------
__global__ __launch_bounds__(256) void gate_pv(
    const _Float16* __restrict__ qhh, const _Float16* __restrict__ khh,
    const _Float16* __restrict__ Z0, const float* __restrict__ dde_w,
    const float* __restrict__ dde_b, float* __restrict__ CTXS)
{
  __shared__ _Float16 gbuf[2][4096];    // [buf][c][ks2][quadk][row][e]
  __shared__ float qs[16][65];          // qhat f32, all 64 comps, +1 pad

  const int tid = threadIdx.x, w = tid >> 6, lane = tid & 63;
  const int mr = lane & 15, quad = lane >> 4;
  const int bh = blockIdx.y, ib = blockIdx.x, jh = blockIdx.z;
  const int i0 = ib * 16;

  {  // stage qhat f32: 16 rows x 64 comps (4 comps/thread)
    int il = tid >> 4, k4 = (tid & 15) * 4;
    union { uint2 u; _Float16 h[4]; } cv;
    cv.u = *(const uint2*)(qhh + pidx(bh * L_SEQ + i0 + il, k4, 64));
    qs[il][k4 + 0] = (float)cv.h[0]; qs[il][k4 + 1] = (float)cv.h[1];
    qs[il][k4 + 2] = (float)cv.h[2]; qs[il][k4 + 3] = (float)cv.h[3];
  }

  float wn[16], bn[4];
  #pragma unroll
  for (int t = 0; t < 16; ++t) wn[t] = uniform_f(dde_w[t]) * (-LOG2E * 0.0625f);
  #pragma unroll
  for (int c = 0; c < 4; ++c) bn[c] = uniform_f(dde_b[c]) * (-LOG2E);

  // score A-frags R_c(qhat) for the i-strip (built once; 32 VGPR)
  u4h8 fr[4][2];
  {
    const _Float16* ap = qhh + ((size_t)(bh * 24 + ib)) * 2 * 512 + lane * 8;
    #pragma unroll
    for (int ks = 0; ks < 2; ++ks) {
      uint4 qa = *(const uint4*)(ap + ks * 512);
      unsigned s0 = ror16(qa.x), s1 = ror16(qa.y), s2 = ror16(qa.z), s3 = ror16(qa.w);
      // R0=(w,-x,-y,-z)  R1=(x,w,-z,y)  R2=(y,z,w,-x)  R3=(z,-y,x,w)
      fr[0][ks].u = make_uint4(qa.x ^ 0x80000000u, qa.y ^ 0x80008000u,
                               qa.z ^ 0x80000000u, qa.w ^ 0x80008000u);
      fr[1][ks].u = make_uint4(s0, s1 ^ 0x00008000u, s2, s3 ^ 0x00008000u);
      fr[2][ks].u = make_uint4(qa.y, qa.x ^ 0x80000000u, qa.w, qa.z ^ 0x80000000u);
      fr[3][ks].u = make_uint4(s1 ^ 0x80000000u, s0, s3 ^ 0x80000000u, s2);
    }
  }

  const int bq = mr >> 2, e = mr & 3;
  // sgn_c(b) nibbles {E,4,8,2} -> 0x284E; tau(c,e) nibbles {0,A,6,C} -> 0xC6A0
  unsigned msk[4];
  #pragma unroll
  for (int c = 0; c < 4; ++c)
    msk[c] = ((((0x284Eu >> (c * 4 + bq)) ^ (0xC6A0u >> (c * 4 + e))) & 1u) << 31);

  f32x4 acc[4][4];                       // [c][nt] PV accumulators (cg = w)
  #pragma unroll
  for (int c = 0; c < 4; ++c)
    #pragma unroll
    for (int nt = 0; nt < 4; ++nt) acc[c][nt] = (f32x4){0.f, 0.f, 0.f, 0.f};

  const int jl = w * 16 + mr;            // this lane's j within the chunk
  const int gw = (jl >> 3) * 128 + (jl & 7) + quad * 32;  // gbuf write base

  #pragma unroll
  for (int ci = 0; ci < 3; ++ci) {
    const int ch = jh * 3 + ci;
    // PV Z0 frags for wave's cg=w slice (independent of score: hoisted)
    u4h8 zb[2][4];
    #pragma unroll
    for (int ks2 = 0; ks2 < 2; ++ks2)
      #pragma unroll
      for (int nt = 0; nt < 4; ++nt)
        zb[ks2][nt].h = *(const f16x8*)(Z0 + (size_t)bh * (256 * 384)
                         + (((size_t)(w * 4 + nt) * 12 + ch * 2 + ks2) * 512) + lane * 8);

    // SCORE: wave w's 16-j subtile, all 4 c (computed ONCE per (i,j,c))
    const _Float16* bp = khh + ((size_t)(bh * 24 + ch * 4 + w)) * 2 * 512 + lane * 8;
    u4h8 kb[2];
    kb[0].h = *(const f16x8*)(bp);
    kb[1].h = *(const f16x8*)(bp + 512);
    f32x4 accS[4];
    #pragma unroll
    for (int c = 0; c < 4; ++c) {
      accS[c] = (f32x4){0.f, 0.f, 0.f, 0.f};
      accS[c] = __builtin_amdgcn_mfma_f32_16x16x32_f16(fr[c][0].h, kb[0].h, accS[c], 0, 0, 0);
      accS[c] = __builtin_amdgcn_mfma_f32_16x16x32_f16(fr[c][1].h, kb[1].h, accS[c], 0, 0, 0);
    }

    // GATE: 16 sigmoids -> f16 A-frag positions in LDS (buffer ci&1)
    #pragma unroll
    for (int r = 0; r < 4; ++r) {
      float S0 = accS[0][r], S1 = accS[1][r], S2 = accS[2][r], S3 = accS[3][r];
      #pragma unroll
      for (int c = 0; c < 4; ++c) {
        float n = bn[c] + wn[c*4+0]*S0 + wn[c*4+1]*S1 + wn[c*4+2]*S2 + wn[c*4+3]*S3;
        float g = __builtin_amdgcn_rcpf(1.f + __builtin_amdgcn_exp2f(n));
        gbuf[ci & 1][c * 1024 + gw + r * 8] = (_Float16)g;
      }
    }
    __syncthreads();                     // single barrier/chunk (dbuf'd gbuf)

    // PV: wave w = cg; all 4 c against its Z0 slice
    #pragma unroll
    for (int ks2 = 0; ks2 < 2; ++ks2) {
      #pragma unroll
      for (int c = 0; c < 4; ++c) {
        f16x8 aa = *(const f16x8*)&gbuf[ci & 1][c * 1024 + ks2 * 512 + lane * 8];
        #pragma unroll
        for (int nt = 0; nt < 4; ++nt)
          acc[c][nt] = __builtin_amdgcn_mfma_f32_16x16x32_f16(aa, zb[ks2][nt].h, acc[c][nt], 0, 0, 0);
      }
    }
  }

  // EPILOGUE (intra-wave Klein butterfly): signed-q multiply, b-reduce
  // (^4,^8), permuted e-stages; lane mr==0 stores f32 partial ctx (float4).
  const int bb_ = bh >> 3, hh = bh & 7;
  float* slab = CTXS + (size_t)jh * 393216;
  #pragma unroll
  for (int nt = 0; nt < 4; ++nt) {
    #pragma unroll
    for (int r = 0; r < 4; ++r) {
      int il = quad * 4 + r;
      float pb[4];
      #pragma unroll
      for (int c = 0; c < 4; ++c) {
        float sq = __uint_as_float(
            __float_as_uint(qs[il][w * 16 + nt * 4 + (bq ^ c)]) ^ msk[c]);
        float v = sq * acc[c][nt][r];
        v += swz_xor<0x101F>(v);
        v += swz_xor<0x201F>(v);
        pb[c] = v;
      }
      float q0 = pb[0] + dpp_xor1(pb[1]);
      float q1 = pb[1] + dpp_xor1(pb[0]);
      float q2 = pb[2] + dpp_xor1(pb[3]);
      float q3 = pb[3] + dpp_xor1(pb[2]);
      float r0 = q0 + dpp_xor2(q2);
      float r1 = q1 + dpp_xor2(q3);
      float r2 = q2 + dpp_xor2(q0);
      float r3 = q3 + dpp_xor2(q1);
      if (mr == 0) {
        *(float4*)&slab[pidx(bb_ * L_SEQ + i0 + il,
                             hh * HD + w * 16 + nt * 4, 512)] =
            make_float4(r0, r1, r2, r3);
      }
    }
  }
}

// ---------------------------------------------------------------------------
// out_gemm: out = (CTXS0 + CTXS1) @ Wo^T. Loads both f32 slabs (32B/lane,
// coalesced), adds in f32, converts to bf16 in-register (single RNE round,
// bit-identical to the unsplit path), MFMA vs packed Wo, f32 atomic-add
// epilogue (K-split x4). grid (16, 12, 4) = 768 blocks.
// ---------------------------------------------------------------------------
__global__ __launch_bounds__(256) void out_gemm(
    const float* __restrict__ S0, const float* __restrict__ S1,
    const __bf16* __restrict__ Wob, float* __restrict__ out)
{
  const int z = blockIdx.z;              // K-split chunk (128 wide = 4 ks)
  const int tid = threadIdx.x;
  const int wave = tid >> 6, lane = tid & 63;
  const int m0 = blockIdx.y * 64 + wave * 16;
  const int n0 = blockIdx.x * 32;
  const int mr = lane & 15, quad = lane >> 4;
  const int KT = 16;                     // 512/32

  f32x4 acc[2];
  acc[0] = (f32x4){0.f, 0.f, 0.f, 0.f};
  acc[1] = (f32x4){0.f, 0.f, 0.f, 0.f};

  const size_t abase = ((size_t)(m0 >> 4) * KT + z * 4) * 512 + lane * 8;
  const __bf16* bp = Wob + ((size_t)(n0 >> 4) * KT + z * 4) * 512 + lane * 8;

  #pragma unroll
  for (int ks = 0; ks < 4; ++ks) {
    const float* a0 = S0 + abase + (size_t)ks * 512;
    const float* a1 = S1 + abase + (size_t)ks * 512;
    float4 x0 = *(const float4*)a0, x1 = *(const float4*)(a0 + 4);
    float4 y0 = *(const float4*)a1, y1 = *(const float4*)(a1 + 4);
    bf16x8 a;
    a[0] = (__bf16)(x0.x + y0.x); a[1] = (__bf16)(x0.y + y0.y);
    a[2] = (__bf16)(x0.z + y0.z); a[3] = (__bf16)(x0.w + y0.w);
    a[4] = (__bf16)(x1.x + y1.x); a[5] = (__bf16)(x1.y + y1.y);
    a[6] = (__bf16)(x1.z + y1.z); a[7] = (__bf16)(x1.w + y1.w);
    #pragma unroll
    for (int nt = 0; nt < 2; ++nt) {
      bf16x8 b = *(const bf16x8*)(bp + ((size_t)nt * KT + ks) * 512);
      acc[nt] = __builtin_amdgcn_mfma_f32_16x16x32_bf16(a, b, acc[nt], 0, 0, 0);
    }
  }

  #pragma unroll
  for (int nt = 0; nt < 2; ++nt) {
    int n = n0 + nt * 16 + mr;
    #pragma unroll
    for (int r = 0; r < 4; ++r) {
      int m = m0 + quad * 4 + r;
      __hip_atomic_fetch_add(&out[(size_t)m * E_DIM + n], acc[nt][r],
                             __ATOMIC_RELAXED, __HIP_MEMORY_SCOPE_AGENT);
    }
  }
}

// ---------------------------------------------------------------------------
// Workspace (8,388,608 B used):
//   [0        ..   524288)  Wob bf16 packed                [whole run]
//   [524288   ..  1310720)  qhat f16 packed                [gemm -> gate_pv]
//   [1310720  ..  2097152)  khat f16 packed                [gemm -> gate_pv]
//   [2097152  ..  5242880)  Z0 f16 packed                  [z_build -> gate_pv]
//   [5242880  ..  8388608)  CTXS f32, 2 slabs x 1572864 B  [gate_pv -> out_gemm]
//     overlays (dead before CTXS written):
//     [5242880 ..  6029312)  vhat f16 packed               [gemm -> z_build]
//     [6029312 ..  8388608)  xb|Wqb|Wkb|Wvb bf16 packed    [cvt -> gemm]
// ---------------------------------------------------------------------------
extern "C" void kernel_launch(void* const* d_in, const int* in_sizes, int n_in,
                              void* d_out, int out_size, void* d_ws, size_t ws_size,
                              hipStream_t stream)
{
  const float* x     = (const float*)d_in[0];
  const float* Wq    = (const float*)d_in[1];
  const float* Wk    = (const float*)d_in[2];
  const float* Wv    = (const float*)d_in[3];
  const float* Wo    = (const float*)d_in[4];
  const float* dde_w = (const float*)d_in[5];
  const float* dde_b = (const float*)d_in[6];
  float* out = (float*)d_out;

  char* ws = (char*)d_ws;
  unsigned short* Wob  = (unsigned short*)(ws + 0);
  _Float16* qhh = (_Float16*)(ws + 524288);
  _Float16* khh = (_Float16*)(ws + 1310720);
  _Float16* Z0h = (_Float16*)(ws + 2097152);
  float* CTXS = (float*)(ws + 5242880);
  _Float16* vhh = (_Float16*)(ws + 5242880);
  unsigned short* xb  = (unsigned short*)(ws + 6029312);
  unsigned short* Wqb = (unsigned short*)(ws + 6815744);
  unsigned short* Wkb = (unsigned short*)(ws + 7340032);
  unsigned short* Wvb = (unsigned short*)(ws + 7864320);

  // 1) fp32 -> bf16 conversions (packed) + zero `out`
  to_bf16_all<<<1792, 256, 0, stream>>>(x, Wq, Wk, Wv, Wo, xb, Wob, out);

  // 2) Q/K/V projections + fused per-atom normalize -> packed f16 (1152 blocks)
  gemm_qkv<<<dim3(32, 12, 3), 256, 0, stream>>>(
      (const __bf16*)xb, (const __bf16*)Wqb, (const __bf16*)Wkb, (const __bf16*)Wvb,
      (float*)qhh, (float*)khh, (float*)vhh, 2 * L_SEQ, E_DIM, E_DIM);

  // 3) PV operand Z0 = khat_b * v_e
  z_build<<<dim3(6, 4, 16), 256, 0, stream>>>(khh, vhh, Z0h);

  // 4) FUSED score+gate+PV, score-once, j-split x2 -> f32 CTXS slabs
  gate_pv<<<dim3(24, 16, 2), 256, 0, stream>>>(qhh, khh, Z0h, dde_w, dde_b, CTXS);

  // 5) output projection: slab-sum + bf16 convert in-register, K-split x4
  out_gemm<<<dim3(16, 12, 4), 256, 0, stream>>>(
      CTXS, CTXS + 393216, (const __bf16*)Wob, out);
}

// Round 9
// 102.990 us; speedup vs baseline: 1.0153x; 1.0153x over previous
//
#include <hip/hip_runtime.h>
#include <math.h>

#define L_SEQ 384
#define E_DIM 512
#define NHEAD 8
#define NBH   16
#define HD    64
#define LOG2E 1.44269504f

typedef __attribute__((ext_vector_type(8))) __bf16 bf16x8;
typedef __attribute__((ext_vector_type(8))) _Float16 f16x8;
typedef __attribute__((ext_vector_type(4))) float f32x4;

union u4h8 { uint4 u; f16x8 h; };

__device__ __forceinline__ float uniform_f(float v) {
  return __uint_as_float(__builtin_amdgcn_readfirstlane(__float_as_uint(v)));
}

__device__ __forceinline__ unsigned f2bf(float f) {   // RNE float->bf16 bits
  unsigned u = __float_as_uint(f);
  return (u + 0x7FFFu + ((u >> 16) & 1u)) >> 16;
}

__device__ __forceinline__ unsigned ror16(unsigned x) { return (x >> 16) | (x << 16); }

// quad_perm DPP: butterfly over the 4 lanes of each aligned 4-lane group
__device__ __forceinline__ float dpp_xor1(float x) {
  return __int_as_float(__builtin_amdgcn_mov_dpp(__float_as_int(x), 0xB1, 0xF, 0xF, 0));
}
__device__ __forceinline__ float dpp_xor2(float x) {
  return __int_as_float(__builtin_amdgcn_mov_dpp(__float_as_int(x), 0x4E, 0xF, 0xF, 0));
}
template <int IMM>
__device__ __forceinline__ float swz_xor(float x) {   // ds_swizzle: imm must be literal
  return __int_as_float(__builtin_amdgcn_ds_swizzle(__float_as_int(x), IMM));
}

// Fragment-packed layout: a wave consumes one (16-row x 32-k) tile as
// lane(quad,mr) -> row=mr, k=quad*8..+7. Pack memory in exactly that order:
// [row/16][k/32][quad=(k>>3)&3][mr=row&15][e=k&7] -> coalesced 16B/lane loads.
__device__ __forceinline__ size_t pidx(int row, int k, int Kd) {
  return ((((size_t)(row >> 4) * (Kd >> 5) + (k >> 5)) * 4 + ((k >> 3) & 3)) * 16
          + (row & 15)) * 8 + (k & 7);
}

// ---------------------------------------------------------------------------
// Convert x|Wq|Wk|Wv (dst1) and Wo (dst2) to bf16 packed; also zero `out`
// (needed by the atomic out-projection; this kernel runs first).
// ---------------------------------------------------------------------------
__global__ __launch_bounds__(256) void to_bf16_all(
    const float* __restrict__ x, const float* __restrict__ Wq,
    const float* __restrict__ Wk, const float* __restrict__ Wv,
    const float* __restrict__ Wo, unsigned short* __restrict__ dst1,
    unsigned short* __restrict__ dst2, float* __restrict__ outz)
{
  int e0 = (blockIdx.x * 256 + threadIdx.x) * 4;
  if (e0 >= 1835008) return;
  if (e0 >= 1441792) {                       // zero the output buffer
    *(float4*)(outz + (e0 - 1441792)) = make_float4(0.f, 0.f, 0.f, 0.f);
    return;
  }
  const float* src; unsigned short* d; int s;
  if (e0 < 393216)       { src = x;  s = e0;           d = dst1; }
  else if (e0 < 655360)  { src = Wq; s = e0 - 393216;  d = dst1 + 393216; }
  else if (e0 < 917504)  { src = Wk; s = e0 - 655360;  d = dst1 + 655360; }
  else if (e0 < 1179648) { src = Wv; s = e0 - 917504;  d = dst1 + 917504; }
  else                   { src = Wo; s = e0 - 1179648; d = dst2; }
  float4 v = *(const float4*)(src + s);
  unsigned lo = f2bf(v.x) | (f2bf(v.y) << 16);
  unsigned hi = f2bf(v.z) | (f2bf(v.w) << 16);
  int row = s >> 9, k = s & 511;
  *(uint2*)(d + pidx(row, k, 512)) = make_uint2(lo, hi);
}

// ---------------------------------------------------------------------------
// QKV GEMM: bf16 MFMA, packed-fragment operands. C = A @ B^T. tile 64x16.
// z selects B/C; epilogue: per-atom quaternion normalize (DPP quad-sum
// across the 4 component lanes) for z<2, then packed-f16 store
// (row=(b*8+h)*L+l, k=d, Kd=64). grid (32, 12, 3) = 1152 blocks.
// ---------------------------------------------------------------------------
__global__ __launch_bounds__(256) void gemm_qkv(
    const __bf16* __restrict__ A, const __bf16* __restrict__ B0,
    const __bf16* __restrict__ B1, const __bf16* __restrict__ B2,
    float* __restrict__ C0, float* __restrict__ C1, float* __restrict__ C2,
    int M, int N, int K)
{
  const int z = blockIdx.z;
  const __bf16* Bm = (z == 0) ? B0 : (z == 1) ? B1 : B2;
  float* Cp = (z == 0) ? C0 : (z == 1) ? C1 : C2;

  const int tid = threadIdx.x;
  const int wave = tid >> 6, lane = tid & 63;
  const int m0 = blockIdx.y * 64 + wave * 16;
  const int n0 = blockIdx.x * 16;
  const int mr = lane & 15, quad = lane >> 4;
  const int KT = K >> 5;

  f32x4 acc = (f32x4){0.f, 0.f, 0.f, 0.f};

  const __bf16* ap = A + (size_t)(m0 >> 4) * KT * 512 + lane * 8;
  const __bf16* bp = Bm + (size_t)(n0 >> 4) * KT * 512 + lane * 8;

  #pragma unroll 4
  for (int ks = 0; ks < KT; ++ks) {
    bf16x8 a = *(const bf16x8*)(ap + (size_t)ks * 512);
    bf16x8 b = *(const bf16x8*)(bp + (size_t)ks * 512);
    acc = __builtin_amdgcn_mfma_f32_16x16x32_bf16(a, b, acc, 0, 0, 0);
  }

  _Float16* Hp = (_Float16*)Cp;
  int n = n0 + mr;
  #pragma unroll
  for (int r = 0; r < 4; ++r) {
    float val = acc[r];
    float s = val * val;
    s += dpp_xor1(s);
    s += dpp_xor2(s);            // |atom|^2 across the 4 component lanes
    float sc = (z == 2) ? 1.f : __builtin_amdgcn_rsqf(fmaxf(s, 1e-30f));
    int m = m0 + quad * 4 + r;
    int b = m / L_SEQ, l = m - b * L_SEQ;
    int row = (b * NHEAD + (n >> 6)) * L_SEQ + l;
    Hp[pidx(row, n & 63, 64)] = (_Float16)(val * sc);
  }
}

// ---------------------------------------------------------------------------
// z_build: Z0[bh][col=(a,b,e)][j] = khat_b(j,a) * v_e(j,a), packed f16.
// grid (6 j-blocks, 4 a-groups, 16 bh) x 256.
// ---------------------------------------------------------------------------
__global__ __launch_bounds__(256) void z_build(
    const _Float16* __restrict__ khh, const _Float16* __restrict__ vhh,
    _Float16* __restrict__ Z0)
{
  const int tid = threadIdx.x;
  const int l = blockIdx.x * 64 + (tid & 63);
  const int a = blockIdx.y * 4 + (tid >> 6);
  const int bh = blockIdx.z;

  size_t off = pidx(bh * L_SEQ + l, a * 4, 64);
  union { uint2 u; _Float16 h[4]; } kk, vv;
  kk.u = *(const uint2*)(khh + off);
  vv.u = *(const uint2*)(vhh + off);

  float kb[4] = {(float)kk.h[0], (float)kk.h[1], (float)kk.h[2], (float)kk.h[3]};
  float ve[4] = {(float)vv.h[0], (float)vv.h[1], (float)vv.h[2], (float)vv.h[3]};
  _Float16* zp = Z0 + (size_t)bh * (256 * 384);
  #pragma unroll
  for (int b = 0; b < 4; ++b)
    #pragma unroll
    for (int e = 0; e < 4; ++e)
      zp[pidx(a * 16 + b * 4 + e, l, 384)] = (_Float16)(kb[b] * ve[e]);
}

// ---------------------------------------------------------------------------
// gate_pv v4 = R7 structure (score-once, no j-split: R8's split regressed)
// + FUSED OUTPUT PROJECTION (out_gemm kernel + CTXB round-trip eliminated).
// Block = 4 waves owns (i-strip 16, bh); grid (24, 16) = 384 blocks.
// Per 64-j chunk (6):
//   SCORE: wave w scores its own 16-j subtile for ALL 4 c (8 MFMA).
//   GATE:  16 sigmoids/lane -> f16 LDS gbuf in MFMA A-frag order
//          (double-buffered -> ONE barrier per chunk).
//   PV:    wave w owns cg=w: for all 4 c, acc[c][nt] += mfma(G_c, Z0_cg).
// Epilogue: intra-wave Klein butterfly -> bf16 ctx tile (16 x 64, ONE RNE
// round as before) into padded LDS; barrier; each wave runs 16 MFMA of
// ctx @ Wo[:, hh-slice]^T (K=64 h-split of the out projection) and
// atomically adds partial out rows (replaces the old z-split atomics).
// ---------------------------------------------------------------------------
__global__ __launch_bounds__(256) void gate_pv(
    const _Float16* __restrict__ qhh, const _Float16* __restrict__ khh,
    const _Float16* __restrict__ Z0, const float* __restrict__ dde_w,
    const float* __restrict__ dde_b, const __bf16* __restrict__ Wob,
    float* __restrict__ out)
{
  __shared__ _Float16 gbuf[2][4096];    // [buf][c][ks2][quadk][row][e]
  __shared__ float qs[16][65];          // qhat f32, all 64 comps, +1 pad
  __shared__ __bf16 ctx_lds[16][72];    // ctx tile, +8 pad: conflict-free b128

  const int tid = threadIdx.x, w = tid >> 6, lane = tid & 63;
  const int mr = lane & 15, quad = lane >> 4;
  const int bh = blockIdx.y, ib = blockIdx.x;
  const int i0 = ib * 16;

  {  // stage qhat f32: 16 rows x 64 comps (4 comps/thread)
    int il = tid >> 4, k4 = (tid & 15) * 4;
    union { uint2 u; _Float16 h[4]; } cv;
    cv.u = *(const uint2*)(qhh + pidx(bh * L_SEQ + i0 + il, k4, 64));
    qs[il][k4 + 0] = (float)cv.h[0]; qs[il][k4 + 1] = (float)cv.h[1];
    qs[il][k4 + 2] = (float)cv.h[2]; qs[il][k4 + 3] = (float)cv.h[3];
  }

  float wn[16], bn[4];
  #pragma unroll
  for (int t = 0; t < 16; ++t) wn[t] = uniform_f(dde_w[t]) * (-LOG2E * 0.0625f);
  #pragma unroll
  for (int c = 0; c < 4; ++c) bn[c] = uniform_f(dde_b[c]) * (-LOG2E);

  // score A-frags R_c(qhat) for the i-strip (built once; 32 VGPR)
  u4h8 fr[4][2];
  {
    const _Float16* ap = qhh + ((size_t)(bh * 24 + ib)) * 2 * 512 + lane * 8;
    #pragma unroll
    for (int ks = 0; ks < 2; ++ks) {
      uint4 qa = *(const uint4*)(ap + ks * 512);
      unsigned s0 = ror16(qa.x), s1 = ror16(qa.y), s2 = ror16(qa.z), s3 = ror16(qa.w);
      // R0=(w,-x,-y,-z)  R1=(x,w,-z,y)  R2=(y,z,w,-x)  R3=(z,-y,x,w)
      fr[0][ks].u = make_uint4(qa.x ^ 0x80000000u, qa.y ^ 0x80008000u,
                               qa.z ^ 0x80000000u, qa.w ^ 0x80008000u);
      fr[1][ks].u = make_uint4(s0, s1 ^ 0x00008000u, s2, s3 ^ 0x00008000u);
      fr[2][ks].u = make_uint4(qa.y, qa.x ^ 0x80000000u, qa.w, qa.z ^ 0x80000000u);
      fr[3][ks].u = make_uint4(s1 ^ 0x80000000u, s0, s3 ^ 0x80000000u, s2);
    }
  }

  const int bq = mr >> 2, e = mr & 3;
  // sgn_c(b) nibbles {E,4,8,2} -> 0x284E; tau(c,e) nibbles {0,A,6,C} -> 0xC6A0
  unsigned msk[4];
  #pragma unroll
  for (int c = 0; c < 4; ++c)
    msk[c] = ((((0x284Eu >> (c * 4 + bq)) ^ (0xC6A0u >> (c * 4 + e))) & 1u) << 31);

  f32x4 acc[4][4];                       // [c][nt] PV accumulators (cg = w)
  #pragma unroll
  for (int c = 0; c < 4; ++c)
    #pragma unroll
    for (int nt = 0; nt < 4; ++nt) acc[c][nt] = (f32x4){0.f, 0.f, 0.f, 0.f};

  const int jl = w * 16 + mr;            // this lane's j within the chunk
  const int gw = (jl >> 3) * 128 + (jl & 7) + quad * 32;  // gbuf write base

  #pragma unroll 2
  for (int ch = 0; ch < 6; ++ch) {
    // PV Z0 frags for wave's cg=w slice (independent of score: hoisted)
    u4h8 zb[2][4];
    #pragma unroll
    for (int ks2 = 0; ks2 < 2; ++ks2)
      #pragma unroll
      for (int nt = 0; nt < 4; ++nt)
        zb[ks2][nt].h = *(const f16x8*)(Z0 + (size_t)bh * (256 * 384)
                         + (((size_t)(w * 4 + nt) * 12 + ch * 2 + ks2) * 512) + lane * 8);

    // SCORE: wave w's 16-j subtile, all 4 c (computed ONCE per (i,j,c))
    const _Float16* bp = khh + ((size_t)(bh * 24 + ch * 4 + w)) * 2 * 512 + lane * 8;
    u4h8 kb[2];
    kb[0].h = *(const f16x8*)(bp);
    kb[1].h = *(const f16x8*)(bp + 512);
    f32x4 accS[4];
    #pragma unroll
    for (int c = 0; c < 4; ++c) {
      accS[c] = (f32x4){0.f, 0.f, 0.f, 0.f};
      accS[c] = __builtin_amdgcn_mfma_f32_16x16x32_f16(fr[c][0].h, kb[0].h, accS[c], 0, 0, 0);
      accS[c] = __builtin_amdgcn_mfma_f32_16x16x32_f16(fr[c][1].h, kb[1].h, accS[c], 0, 0, 0);
    }

    // GATE: 16 sigmoids -> f16 A-frag positions in LDS (buffer ch&1)
    #pragma unroll
    for (int r = 0; r < 4; ++r) {
      float S0 = accS[0][r], S1 = accS[1][r], S2 = accS[2][r], S3 = accS[3][r];
      #pragma unroll
      for (int c = 0; c < 4; ++c) {
        float n = bn[c] + wn[c*4+0]*S0 + wn[c*4+1]*S1 + wn[c*4+2]*S2 + wn[c*4+3]*S3;
        float g = __builtin_amdgcn_rcpf(1.f + __builtin_amdgcn_exp2f(n));
        gbuf[ch & 1][c * 1024 + gw + r * 8] = (_Float16)g;
      }
    }
    __syncthreads();                     // single barrier/chunk (dbuf'd gbuf)

    // PV: wave w = cg; all 4 c against its Z0 slice
    #pragma unroll
    for (int ks2 = 0; ks2 < 2; ++ks2) {
      #pragma unroll
      for (int c = 0; c < 4; ++c) {
        f16x8 aa = *(const f16x8*)&gbuf[ch & 1][c * 1024 + ks2 * 512 + lane * 8];
        #pragma unroll
        for (int nt = 0; nt < 4; ++nt)
          acc[c][nt] = __builtin_amdgcn_mfma_f32_16x16x32_f16(aa, zb[ks2][nt].h, acc[c][nt], 0, 0, 0);
      }
    }
  }

  // EPILOGUE 1 (intra-wave Klein butterfly): signed-q multiply, b-reduce
  // (^4,^8), permuted e-stages; lane mr==0 stores bf16 ctx (ONE RNE round,
  // same as the old CTXB path) into the padded LDS tile.
  #pragma unroll
  for (int nt = 0; nt < 4; ++nt) {
    #pragma unroll
    for (int r = 0; r < 4; ++r) {
      int il = quad * 4 + r;
      float pb[4];
      #pragma unroll
      for (int c = 0; c < 4; ++c) {
        float sq = __uint_as_float(
            __float_as_uint(qs[il][w * 16 + nt * 4 + (bq ^ c)]) ^ msk[c]);
        float v = sq * acc[c][nt][r];
        v += swz_xor<0x101F>(v);
        v += swz_xor<0x201F>(v);
        pb[c] = v;
      }
      float q0 = pb[0] + dpp_xor1(pb[1]);
      float q1 = pb[1] + dpp_xor1(pb[0]);
      float q2 = pb[2] + dpp_xor1(pb[3]);
      float q3 = pb[3] + dpp_xor1(pb[2]);
      float r0 = q0 + dpp_xor2(q2);
      float r1 = q1 + dpp_xor2(q3);
      float r2 = q2 + dpp_xor2(q0);
      float r3 = q3 + dpp_xor2(q1);
      if (mr == 0) {
        ctx_lds[il][w * 16 + nt * 4 + 0] = (__bf16)r0;
        ctx_lds[il][w * 16 + nt * 4 + 1] = (__bf16)r1;
        ctx_lds[il][w * 16 + nt * 4 + 2] = (__bf16)r2;
        ctx_lds[il][w * 16 + nt * 4 + 3] = (__bf16)r3;
      }
    }
  }
  __syncthreads();

  // EPILOGUE 2 (fused out-projection, K=64 h-split): each wave covers
  // n = w*128 .. +128 (8 n-tiles); A-frag from ctx_lds (row=mr, k=quad*8+e),
  // B-frag from packed Wob k-slice [hh*64, hh*64+64); f32 atomic-add.
  const int bb_ = bh >> 3, hh = bh & 7;
  const int m_base = bb_ * L_SEQ + i0;
  bf16x8 af[2];
  #pragma unroll
  for (int ks2 = 0; ks2 < 2; ++ks2)
    af[ks2] = *(const bf16x8*)&ctx_lds[mr][ks2 * 32 + quad * 8];
  #pragma unroll
  for (int nt2 = 0; nt2 < 8; ++nt2) {
    const int ntile = w * 8 + nt2;       // n-tile index over 512
    f32x4 accO = (f32x4){0.f, 0.f, 0.f, 0.f};
    #pragma unroll
    for (int ks2 = 0; ks2 < 2; ++ks2) {
      bf16x8 b = *(const bf16x8*)(Wob + ((size_t)ntile * 16 + hh * 2 + ks2) * 512 + lane * 8);
      accO = __builtin_amdgcn_mfma_f32_16x16x32_bf16(af[ks2], b, accO, 0, 0, 0);
    }
    const int n = ntile * 16 + mr;
    #pragma unroll
    for (int r = 0; r < 4; ++r) {
      int m = m_base + quad * 4 + r;
      __hip_atomic_fetch_add(&out[(size_t)m * E_DIM + n], accO[r],
                             __ATOMIC_RELAXED, __HIP_MEMORY_SCOPE_AGENT);
    }
  }
}

// ---------------------------------------------------------------------------
// Workspace (8,388,608 B used):
//   [0        ..   524288)  Wob bf16 packed                [whole run]
//   [524288   ..  1310720)  qhat f16 packed                [gemm -> gate_pv]
//   [1310720  ..  2097152)  khat f16 packed                [gemm -> gate_pv]
//   [2097152  ..  5242880)  Z0 f16 packed                  [z_build -> gate_pv]
//   [5242880  ..  6029312)  vhat f16 packed                [gemm -> z_build]
//   [6029312  ..  8388608)  xb|Wqb|Wkb|Wvb bf16 packed     [cvt -> gemm]
// ---------------------------------------------------------------------------
extern "C" void kernel_launch(void* const* d_in, const int* in_sizes, int n_in,
                              void* d_out, int out_size, void* d_ws, size_t ws_size,
                              hipStream_t stream)
{
  const float* x     = (const float*)d_in[0];
  const float* Wq    = (const float*)d_in[1];
  const float* Wk    = (const float*)d_in[2];
  const float* Wv    = (const float*)d_in[3];
  const float* Wo    = (const float*)d_in[4];
  const float* dde_w = (const float*)d_in[5];
  const float* dde_b = (const float*)d_in[6];
  float* out = (float*)d_out;

  char* ws = (char*)d_ws;
  unsigned short* Wob  = (unsigned short*)(ws + 0);
  _Float16* qhh = (_Float16*)(ws + 524288);
  _Float16* khh = (_Float16*)(ws + 1310720);
  _Float16* Z0h = (_Float16*)(ws + 2097152);
  _Float16* vhh = (_Float16*)(ws + 5242880);
  unsigned short* xb  = (unsigned short*)(ws + 6029312);
  unsigned short* Wqb = (unsigned short*)(ws + 6815744);
  unsigned short* Wkb = (unsigned short*)(ws + 7340032);
  unsigned short* Wvb = (unsigned short*)(ws + 7864320);

  // 1) fp32 -> bf16 conversions (packed) + zero `out`
  to_bf16_all<<<1792, 256, 0, stream>>>(x, Wq, Wk, Wv, Wo, xb, Wob, out);

  // 2) Q/K/V projections + fused per-atom normalize -> packed f16 (1152 blocks)
  gemm_qkv<<<dim3(32, 12, 3), 256, 0, stream>>>(
      (const __bf16*)xb, (const __bf16*)Wqb, (const __bf16*)Wkb, (const __bf16*)Wvb,
      (float*)qhh, (float*)khh, (float*)vhh, 2 * L_SEQ, E_DIM, E_DIM);

  // 3) PV operand Z0 = khat_b * v_e
  z_build<<<dim3(6, 4, 16), 256, 0, stream>>>(khh, vhh, Z0h);

  // 4) FUSED score+gate+PV+out-projection -> atomic f32 out (no CTXB,
  //    no out_gemm kernel)
  gate_pv<<<dim3(24, 16), 256, 0, stream>>>(
      qhh, khh, Z0h, dde_w, dde_b, (const __bf16*)Wob, out);
}

// Round 10
// 101.375 us; speedup vs baseline: 1.0314x; 1.0159x over previous
//
#include <hip/hip_runtime.h>
#include <math.h>

#define L_SEQ 384
#define E_DIM 512
#define NHEAD 8
#define NBH   16
#define HD    64
#define LOG2E 1.44269504f

typedef __attribute__((ext_vector_type(8))) __bf16 bf16x8;
typedef __attribute__((ext_vector_type(8))) _Float16 f16x8;
typedef __attribute__((ext_vector_type(4))) float f32x4;

union u4h8 { uint4 u; f16x8 h; };

__device__ __forceinline__ float uniform_f(float v) {
  return __uint_as_float(__builtin_amdgcn_readfirstlane(__float_as_uint(v)));
}

__device__ __forceinline__ unsigned f2bf(float f) {   // RNE float->bf16 bits
  unsigned u = __float_as_uint(f);
  return (u + 0x7FFFu + ((u >> 16) & 1u)) >> 16;
}

__device__ __forceinline__ unsigned ror16(unsigned x) { return (x >> 16) | (x << 16); }

// quad_perm DPP helpers (aligned 4-lane groups)
__device__ __forceinline__ float dpp_xor1(float x) {
  return __int_as_float(__builtin_amdgcn_mov_dpp(__float_as_int(x), 0xB1, 0xF, 0xF, 0));
}
__device__ __forceinline__ float dpp_xor2(float x) {
  return __int_as_float(__builtin_amdgcn_mov_dpp(__float_as_int(x), 0x4E, 0xF, 0xF, 0));
}
template <int PAT>
__device__ __forceinline__ float quad_bcast(float x) {
  return __int_as_float(__builtin_amdgcn_mov_dpp(__float_as_int(x), PAT, 0xF, 0xF, 0));
}
template <int IMM>
__device__ __forceinline__ float swz_xor(float x) {   // ds_swizzle: imm must be literal
  return __int_as_float(__builtin_amdgcn_ds_swizzle(__float_as_int(x), IMM));
}

// Fragment-packed layout: a wave consumes one (16-row x 32-k) tile as
// lane(quad,mr) -> row=mr, k=quad*8..+7. Pack memory in exactly that order:
// [row/16][k/32][quad=(k>>3)&3][mr=row&15][e=k&7] -> coalesced 16B/lane loads.
__device__ __forceinline__ size_t pidx(int row, int k, int Kd) {
  return ((((size_t)(row >> 4) * (Kd >> 5) + (k >> 5)) * 4 + ((k >> 3) & 3)) * 16
          + (row & 15)) * 8 + (k & 7);
}

// ---------------------------------------------------------------------------
// Convert x|Wq|Wk|Wv (dst1) and Wo (dst2) to bf16 packed; also zero `out`
// (needed by the atomic out-projection; this kernel runs first).
// ---------------------------------------------------------------------------
__global__ __launch_bounds__(256) void to_bf16_all(
    const float* __restrict__ x, const float* __restrict__ Wq,
    const float* __restrict__ Wk, const float* __restrict__ Wv,
    const float* __restrict__ Wo, unsigned short* __restrict__ dst1,
    unsigned short* __restrict__ dst2, float* __restrict__ outz)
{
  int e0 = (blockIdx.x * 256 + threadIdx.x) * 4;
  if (e0 >= 1835008) return;
  if (e0 >= 1441792) {                       // zero the output buffer
    *(float4*)(outz + (e0 - 1441792)) = make_float4(0.f, 0.f, 0.f, 0.f);
    return;
  }
  const float* src; unsigned short* d; int s;
  if (e0 < 393216)       { src = x;  s = e0;           d = dst1; }
  else if (e0 < 655360)  { src = Wq; s = e0 - 393216;  d = dst1 + 393216; }
  else if (e0 < 917504)  { src = Wk; s = e0 - 655360;  d = dst1 + 655360; }
  else if (e0 < 1179648) { src = Wv; s = e0 - 917504;  d = dst1 + 917504; }
  else                   { src = Wo; s = e0 - 1179648; d = dst2; }
  float4 v = *(const float4*)(src + s);
  unsigned lo = f2bf(v.x) | (f2bf(v.y) << 16);
  unsigned hi = f2bf(v.z) | (f2bf(v.w) << 16);
  int row = s >> 9, k = s & 511;
  *(uint2*)(d + pidx(row, k, 512)) = make_uint2(lo, hi);
}

// ---------------------------------------------------------------------------
// QKV GEMM v2: z=0 -> Q (16 MFMA, normalize, qhat); z=1 -> K AND V in one
// block (32 MFMA, A-loads shared): epilogue normalizes K (DPP quad-sum),
// stores khat, and builds Z0 DIRECTLY from in-register khat (f32) and
// valV via 4 quad-broadcast DPPs: lane(comp) writes Z0[a*16+comp*4+e][j]
// = khat_comp * v_e. z_build kernel + vhat tensor ELIMINATED.
// grid (32, 12, 2) = 768 blocks; total MFMA count unchanged.
// ---------------------------------------------------------------------------
__global__ __launch_bounds__(256) void gemm_qkv(
    const __bf16* __restrict__ A, const __bf16* __restrict__ B0,
    const __bf16* __restrict__ B1, const __bf16* __restrict__ B2,
    _Float16* __restrict__ qhh, _Float16* __restrict__ khh,
    _Float16* __restrict__ Z0)
{
  const int z = blockIdx.z;
  const int tid = threadIdx.x;
  const int wave = tid >> 6, lane = tid & 63;
  const int m0 = blockIdx.y * 64 + wave * 16;
  const int n0 = blockIdx.x * 16;
  const int mr = lane & 15, quad = lane >> 4;
  const int KT = 16;                         // 512/32

  const __bf16* ap = A + (size_t)(m0 >> 4) * KT * 512 + lane * 8;
  const int n = n0 + mr;

  if (z == 0) {                              // ---- Q projection ----
    const __bf16* bp = B0 + (size_t)(n0 >> 4) * KT * 512 + lane * 8;
    f32x4 acc = (f32x4){0.f, 0.f, 0.f, 0.f};
    #pragma unroll 4
    for (int ks = 0; ks < KT; ++ks) {
      bf16x8 a = *(const bf16x8*)(ap + (size_t)ks * 512);
      bf16x8 b = *(const bf16x8*)(bp + (size_t)ks * 512);
      acc = __builtin_amdgcn_mfma_f32_16x16x32_bf16(a, b, acc, 0, 0, 0);
    }
    #pragma unroll
    for (int r = 0; r < 4; ++r) {
      float val = acc[r];
      float s = val * val;
      s += dpp_xor1(s);
      s += dpp_xor2(s);                      // |atom|^2 across component lanes
      float sc = __builtin_amdgcn_rsqf(fmaxf(s, 1e-30f));
      int m = m0 + quad * 4 + r;
      int b = m / L_SEQ, l = m - b * L_SEQ;
      int row = (b * NHEAD + (n >> 6)) * L_SEQ + l;
      qhh[pidx(row, n & 63, 64)] = (_Float16)(val * sc);
    }
  } else {                                   // ---- K + V fused ----
    const __bf16* bpk = B1 + (size_t)(n0 >> 4) * KT * 512 + lane * 8;
    const __bf16* bpv = B2 + (size_t)(n0 >> 4) * KT * 512 + lane * 8;
    f32x4 accK = (f32x4){0.f, 0.f, 0.f, 0.f};
    f32x4 accV = (f32x4){0.f, 0.f, 0.f, 0.f};
    #pragma unroll 4
    for (int ks = 0; ks < KT; ++ks) {
      bf16x8 a = *(const bf16x8*)(ap + (size_t)ks * 512);
      bf16x8 bk = *(const bf16x8*)(bpk + (size_t)ks * 512);
      bf16x8 bv = *(const bf16x8*)(bpv + (size_t)ks * 512);
      accK = __builtin_amdgcn_mfma_f32_16x16x32_bf16(a, bk, accK, 0, 0, 0);
      accV = __builtin_amdgcn_mfma_f32_16x16x32_bf16(a, bv, accV, 0, 0, 0);
    }
    const int a_atom = (n & 63) >> 2, comp = n & 3;
    #pragma unroll
    for (int r = 0; r < 4; ++r) {
      float vk = accK[r], vv = accV[r];
      float s = vk * vk;
      s += dpp_xor1(s);
      s += dpp_xor2(s);
      float kn = vk * __builtin_amdgcn_rsqf(fmaxf(s, 1e-30f));
      int m = m0 + quad * 4 + r;
      int b = m / L_SEQ, l = m - b * L_SEQ;
      int bh = b * NHEAD + (n >> 6);
      int row = bh * L_SEQ + l;
      khh[pidx(row, n & 63, 64)] = (_Float16)kn;
      // v_e across the 4 component lanes (quad-aligned)
      float v0 = quad_bcast<0x00>(vv), v1 = quad_bcast<0x55>(vv);
      float v2 = quad_bcast<0xAA>(vv), v3 = quad_bcast<0xFF>(vv);
      _Float16* zp = Z0 + (size_t)bh * (256 * 384);
      int colb = a_atom * 16 + comp * 4;
      zp[pidx(colb + 0, l, 384)] = (_Float16)(kn * v0);
      zp[pidx(colb + 1, l, 384)] = (_Float16)(kn * v1);
      zp[pidx(colb + 2, l, 384)] = (_Float16)(kn * v2);
      zp[pidx(colb + 3, l, 384)] = (_Float16)(kn * v3);
    }
  }
}

// ---------------------------------------------------------------------------
// gate_pv v5 = R9 structure + kb PING-PONG PREFETCH: score no longer waits
// on same-chunk loads (vmcnt is issue-ordered: the old zb-then-kb order made
// score drain ALL 10 outstanding loads, exposing ~400-500 cyc x 6 chunks).
// kb(ch+1) is issued right after score(ch); zb keeps its natural slack
// (consumed only after the barrier).
// Block = 4 waves owns (i-strip 16, bh); grid (24, 16) = 384 blocks.
// Epilogues unchanged: Klein butterfly -> bf16 ctx in LDS -> fused
// out-projection (K=64 h-split) with f32 atomic-add.
// ---------------------------------------------------------------------------
__global__ __launch_bounds__(256) void gate_pv(
    const _Float16* __restrict__ qhh, const _Float16* __restrict__ khh,
    const _Float16* __restrict__ Z0, const float* __restrict__ dde_w,
    const float* __restrict__ dde_b, const __bf16* __restrict__ Wob,
    float* __restrict__ out)
{
  __shared__ _Float16 gbuf[2][4096];    // [buf][c][ks2][quadk][row][e]
  __shared__ float qs[16][65];          // qhat f32, all 64 comps, +1 pad
  __shared__ __bf16 ctx_lds[16][72];    // ctx tile, +8 pad: conflict-free b128

  const int tid = threadIdx.x, w = tid >> 6, lane = tid & 63;
  const int mr = lane & 15, quad = lane >> 4;
  const int bh = blockIdx.y, ib = blockIdx.x;
  const int i0 = ib * 16;

  {  // stage qhat f32: 16 rows x 64 comps (4 comps/thread)
    int il = tid >> 4, k4 = (tid & 15) * 4;
    union { uint2 u; _Float16 h[4]; } cv;
    cv.u = *(const uint2*)(qhh + pidx(bh * L_SEQ + i0 + il, k4, 64));
    qs[il][k4 + 0] = (float)cv.h[0]; qs[il][k4 + 1] = (float)cv.h[1];
    qs[il][k4 + 2] = (float)cv.h[2]; qs[il][k4 + 3] = (float)cv.h[3];
  }

  float wn[16], bn[4];
  #pragma unroll
  for (int t = 0; t < 16; ++t) wn[t] = uniform_f(dde_w[t]) * (-LOG2E * 0.0625f);
  #pragma unroll
  for (int c = 0; c < 4; ++c) bn[c] = uniform_f(dde_b[c]) * (-LOG2E);

  // score A-frags R_c(qhat) for the i-strip (built once; 32 VGPR)
  u4h8 fr[4][2];
  {
    const _Float16* ap = qhh + ((size_t)(bh * 24 + ib)) * 2 * 512 + lane * 8;
    #pragma unroll
    for (int ks = 0; ks < 2; ++ks) {
      uint4 qa = *(const uint4*)(ap + ks * 512);
      unsigned s0 = ror16(qa.x), s1 = ror16(qa.y), s2 = ror16(qa.z), s3 = ror16(qa.w);
      // R0=(w,-x,-y,-z)  R1=(x,w,-z,y)  R2=(y,z,w,-x)  R3=(z,-y,x,w)
      fr[0][ks].u = make_uint4(qa.x ^ 0x80000000u, qa.y ^ 0x80008000u,
                               qa.z ^ 0x80000000u, qa.w ^ 0x80008000u);
      fr[1][ks].u = make_uint4(s0, s1 ^ 0x00008000u, s2, s3 ^ 0x00008000u);
      fr[2][ks].u = make_uint4(qa.y, qa.x ^ 0x80000000u, qa.w, qa.z ^ 0x80000000u);
      fr[3][ks].u = make_uint4(s1 ^ 0x80000000u, s0, s3 ^ 0x80000000u, s2);
    }
  }

  const int bq = mr >> 2, e = mr & 3;
  // sgn_c(b) nibbles {E,4,8,2} -> 0x284E; tau(c,e) nibbles {0,A,6,C} -> 0xC6A0
  unsigned msk[4];
  #pragma unroll
  for (int c = 0; c < 4; ++c)
    msk[c] = ((((0x284Eu >> (c * 4 + bq)) ^ (0xC6A0u >> (c * 4 + e))) & 1u) << 31);

  f32x4 acc[4][4];                       // [c][nt] PV accumulators (cg = w)
  #pragma unroll
  for (int c = 0; c < 4; ++c)
    #pragma unroll
    for (int nt = 0; nt < 4; ++nt) acc[c][nt] = (f32x4){0.f, 0.f, 0.f, 0.f};

  const int jl = w * 16 + mr;            // this lane's j within the chunk
  const int gw = (jl >> 3) * 128 + (jl & 7) + quad * 32;  // gbuf write base

  // kb ping-pong prefetch: prologue loads chunk 0
  u4h8 kbp[2][2];                        // [buf][ks]
  {
    const _Float16* bp = khh + ((size_t)(bh * 24 + w)) * 2 * 512 + lane * 8;
    kbp[0][0].h = *(const f16x8*)(bp);
    kbp[0][1].h = *(const f16x8*)(bp + 512);
  }

  #pragma unroll
  for (int ch = 0; ch < 6; ++ch) {
    const int cur = ch & 1, nxt = cur ^ 1;
    // PV Z0 frags (consumed only after the barrier: latency self-hiding)
    u4h8 zb[2][4];
    #pragma unroll
    for (int ks2 = 0; ks2 < 2; ++ks2)
      #pragma unroll
      for (int nt = 0; nt < 4; ++nt)
        zb[ks2][nt].h = *(const f16x8*)(Z0 + (size_t)bh * (256 * 384)
                         + (((size_t)(w * 4 + nt) * 12 + ch * 2 + ks2) * 512) + lane * 8);

    // SCORE with the PREFETCHED kb (no same-chunk load dependency)
    f32x4 accS[4];
    #pragma unroll
    for (int c = 0; c < 4; ++c) {
      accS[c] = (f32x4){0.f, 0.f, 0.f, 0.f};
      accS[c] = __builtin_amdgcn_mfma_f32_16x16x32_f16(fr[c][0].h, kbp[cur][0].h, accS[c], 0, 0, 0);
      accS[c] = __builtin_amdgcn_mfma_f32_16x16x32_f16(fr[c][1].h, kbp[cur][1].h, accS[c], 0, 0, 0);
    }

    // prefetch kb for chunk ch+1 (hides under gate+barrier+PV)
    if (ch < 5) {
      const _Float16* bp = khh + ((size_t)(bh * 24 + (ch + 1) * 4 + w)) * 2 * 512 + lane * 8;
      kbp[nxt][0].h = *(const f16x8*)(bp);
      kbp[nxt][1].h = *(const f16x8*)(bp + 512);
    }

    // GATE: 16 sigmoids -> f16 A-frag positions in LDS (buffer cur)
    #pragma unroll
    for (int r = 0; r < 4; ++r) {
      float S0 = accS[0][r], S1 = accS[1][r], S2 = accS[2][r], S3 = accS[3][r];
      #pragma unroll
      for (int c = 0; c < 4; ++c) {
        float n = bn[c] + wn[c*4+0]*S0 + wn[c*4+1]*S1 + wn[c*4+2]*S2 + wn[c*4+3]*S3;
        float g = __builtin_amdgcn_rcpf(1.f + __builtin_amdgcn_exp2f(n));
        gbuf[cur][c * 1024 + gw + r * 8] = (_Float16)g;
      }
    }
    __syncthreads();                     // single barrier/chunk (dbuf'd gbuf)

    // PV: wave w = cg; all 4 c against its Z0 slice
    #pragma unroll
    for (int ks2 = 0; ks2 < 2; ++ks2) {
      #pragma unroll
      for (int c = 0; c < 4; ++c) {
        f16x8 aa = *(const f16x8*)&gbuf[cur][c * 1024 + ks2 * 512 + lane * 8];
        #pragma unroll
        for (int nt = 0; nt < 4; ++nt)
          acc[c][nt] = __builtin_amdgcn_mfma_f32_16x16x32_f16(aa, zb[ks2][nt].h, acc[c][nt], 0, 0, 0);
      }
    }
  }

  // EPILOGUE 1 (intra-wave Klein butterfly): signed-q multiply, b-reduce
  // (^4,^8), permuted e-stages; lane mr==0 stores bf16 ctx (ONE RNE round)
  // into the padded LDS tile.
  #pragma unroll
  for (int nt = 0; nt < 4; ++nt) {
    #pragma unroll
    for (int r = 0; r < 4; ++r) {
      int il = quad * 4 + r;
      float pb[4];
      #pragma unroll
      for (int c = 0; c < 4; ++c) {
        float sq = __uint_as_float(
            __float_as_uint(qs[il][w * 16 + nt * 4 + (bq ^ c)]) ^ msk[c]);
        float v = sq * acc[c][nt][r];
        v += swz_xor<0x101F>(v);
        v += swz_xor<0x201F>(v);
        pb[c] = v;
      }
      float q0 = pb[0] + dpp_xor1(pb[1]);
      float q1 = pb[1] + dpp_xor1(pb[0]);
      float q2 = pb[2] + dpp_xor1(pb[3]);
      float q3 = pb[3] + dpp_xor1(pb[2]);
      float r0 = q0 + dpp_xor2(q2);
      float r1 = q1 + dpp_xor2(q3);
      float r2 = q2 + dpp_xor2(q0);
      float r3 = q3 + dpp_xor2(q1);
      if (mr == 0) {
        ctx_lds[il][w * 16 + nt * 4 + 0] = (__bf16)r0;
        ctx_lds[il][w * 16 + nt * 4 + 1] = (__bf16)r1;
        ctx_lds[il][w * 16 + nt * 4 + 2] = (__bf16)r2;
        ctx_lds[il][w * 16 + nt * 4 + 3] = (__bf16)r3;
      }
    }
  }
  __syncthreads();

  // EPILOGUE 2 (fused out-projection, K=64 h-split): each wave covers
  // n = w*128 .. +128 (8 n-tiles); A-frag from ctx_lds, B-frag from packed
  // Wob k-slice [hh*64, hh*64+64); f32 atomic-add.
  const int bb_ = bh >> 3, hh = bh & 7;
  const int m_base = bb_ * L_SEQ + i0;
  bf16x8 af[2];
  #pragma unroll
  for (int ks2 = 0; ks2 < 2; ++ks2)
    af[ks2] = *(const bf16x8*)&ctx_lds[mr][ks2 * 32 + quad * 8];
  #pragma unroll
  for (int nt2 = 0; nt2 < 8; ++nt2) {
    const int ntile = w * 8 + nt2;       // n-tile index over 512
    f32x4 accO = (f32x4){0.f, 0.f, 0.f, 0.f};
    #pragma unroll
    for (int ks2 = 0; ks2 < 2; ++ks2) {
      bf16x8 b = *(const bf16x8*)(Wob + ((size_t)ntile * 16 + hh * 2 + ks2) * 512 + lane * 8);
      accO = __builtin_amdgcn_mfma_f32_16x16x32_bf16(af[ks2], b, accO, 0, 0, 0);
    }
    const int n = ntile * 16 + mr;
    #pragma unroll
    for (int r = 0; r < 4; ++r) {
      int m = m_base + quad * 4 + r;
      __hip_atomic_fetch_add(&out[(size_t)m * E_DIM + n], accO[r],
                             __ATOMIC_RELAXED, __HIP_MEMORY_SCOPE_AGENT);
    }
  }
}

// ---------------------------------------------------------------------------
// Workspace (8,388,608 B used):
//   [0        ..   524288)  Wob bf16 packed                [whole run]
//   [524288   ..  1310720)  qhat f16 packed                [gemm -> gate_pv]
//   [1310720  ..  2097152)  khat f16 packed                [gemm -> gate_pv]
//   [2097152  ..  5242880)  Z0 f16 packed                  [gemm -> gate_pv]
//   [6029312  ..  8388608)  xb|Wqb|Wkb|Wvb bf16 packed     [cvt -> gemm]
// (z_build + vhat eliminated: Z0 is built in gemm_qkv's z=1 epilogue.)
// ---------------------------------------------------------------------------
extern "C" void kernel_launch(void* const* d_in, const int* in_sizes, int n_in,
                              void* d_out, int out_size, void* d_ws, size_t ws_size,
                              hipStream_t stream)
{
  const float* x     = (const float*)d_in[0];
  const float* Wq    = (const float*)d_in[1];
  const float* Wk    = (const float*)d_in[2];
  const float* Wv    = (const float*)d_in[3];
  const float* Wo    = (const float*)d_in[4];
  const float* dde_w = (const float*)d_in[5];
  const float* dde_b = (const float*)d_in[6];
  float* out = (float*)d_out;

  char* ws = (char*)d_ws;
  unsigned short* Wob  = (unsigned short*)(ws + 0);
  _Float16* qhh = (_Float16*)(ws + 524288);
  _Float16* khh = (_Float16*)(ws + 1310720);
  _Float16* Z0h = (_Float16*)(ws + 2097152);
  unsigned short* xb  = (unsigned short*)(ws + 6029312);
  unsigned short* Wqb = (unsigned short*)(ws + 6815744);
  unsigned short* Wkb = (unsigned short*)(ws + 7340032);
  unsigned short* Wvb = (unsigned short*)(ws + 7864320);

  // 1) fp32 -> bf16 conversions (packed) + zero `out`
  to_bf16_all<<<1792, 256, 0, stream>>>(x, Wq, Wk, Wv, Wo, xb, Wob, out);

  // 2) Q | K+V projections; K+V epilogue emits khat AND Z0 (no z_build)
  gemm_qkv<<<dim3(32, 12, 2), 256, 0, stream>>>(
      (const __bf16*)xb, (const __bf16*)Wqb, (const __bf16*)Wkb, (const __bf16*)Wvb,
      qhh, khh, Z0h);

  // 3) FUSED score+gate+PV+out-projection -> atomic f32 out
  gate_pv<<<dim3(24, 16), 256, 0, stream>>>(
      qhh, khh, Z0h, dde_w, dde_b, (const __bf16*)Wob, out);
}